// Round 4
// baseline (165.294 us; speedup 1.0000x reference)
//
#include <hip/hip_runtime.h>
#include <hip/hip_bf16.h>

typedef __attribute__((ext_vector_type(8))) short bf16x8;
typedef __attribute__((ext_vector_type(4))) short bf16x4;
typedef __attribute__((ext_vector_type(4))) float f32x4;

#define HS 128
#define ED 1024
#define TT 2048
#define NBATCH 8
#define NROWS (NBATCH * TT)  // 16384
#define CHUNKS 4             // max kv chunks of 512
#define TPC 8                // 64-kv tiles per chunk

__device__ __forceinline__ short bf16rne(float f) {
    unsigned u = __builtin_bit_cast(unsigned, f);
    u = u + 0x7fffu + ((u >> 16) & 1u);
    return (short)(u >> 16);
}

// async global->LDS, 16B per lane. LDS dest must be wave-uniform (HW adds lane*16).
__device__ __forceinline__ void gl_lds16(const void* g, void* l) {
    __builtin_amdgcn_global_load_lds(
        (const __attribute__((address_space(1))) unsigned int*)g,
        (__attribute__((address_space(3))) unsigned int*)l, 16, 0, 0);
}

// Stage NCALLS*4KB of a row-major global tile into XOR-swizzled LDS.
// LDS row = 1<<RBL2 bytes; swizzle: colU = colS ^ ((row&7)<<4) (involution).
// Linear LDS dest + inverse-swizzled global source (rule 21).
template <int NCALLS, int RBL2>
__device__ __forceinline__ void stage_tile(const char* gbase, void* lds,
                                           int gpitch, int tid, int wv) {
#pragma unroll
    for (int c = 0; c < NCALLS; ++c) {
        const int o = c * 4096 + tid * 16;
        const int row = o >> RBL2;
        const int colU = (o & ((1 << RBL2) - 1)) ^ ((row & 7) << 4);
        const char* g = gbase + (size_t)row * gpitch + colU;
        char* l = (char*)lds + c * 4096 + wv * 1024;  // wave-uniform
        gl_lds16(g, l);
    }
}

// swizzled ds_read of a bf16x8 fragment
__device__ __forceinline__ bf16x8 lds_rd7(const short* lds, int row, int colE) {
    const int o = (row << 7) + (((colE * 2) & 127) ^ ((row & 7) << 4));
    return *reinterpret_cast<const bf16x8*>((const char*)lds + o);
}
__device__ __forceinline__ bf16x8 lds_rd8(const short* lds, int row, int colE) {
    const int o = (row << 8) + (((colE * 2) & 255) ^ ((row & 7) << 4));
    return *reinterpret_cast<const bf16x8*>((const char*)lds + o);
}

// ---------- W transpose: [1024][128] f32 -> [128][1024] bf16 ----------
__global__ void k_wtrans(const float* __restrict__ Wk, const float* __restrict__ Wv,
                         short* __restrict__ WkT, short* __restrict__ WvT) {
    const float* W = blockIdx.y ? Wv : Wk;
    short* WT = blockIdx.y ? WvT : WkT;
    __shared__ float tile[16][128];
    const int k0 = blockIdx.x * 16;
    const int t = threadIdx.x;
#pragma unroll
    for (int i = 0; i < 8; ++i) {
        int idx = t + i * 256;
        tile[idx >> 7][idx & 127] = W[(size_t)(k0 + (idx >> 7)) * HS + (idx & 127)];
    }
    __syncthreads();
    const int n = t >> 1;
    const int h = (t & 1) * 8;
    bf16x8 o;
#pragma unroll
    for (int i = 0; i < 8; ++i) o[i] = bf16rne(tile[h + i][n]);
    *reinterpret_cast<bf16x8*>(&WT[(size_t)n * ED + k0 + h]) = o;
}

// ---------- projection: one side per block. grid (2 sides, 256 row-tiles) ----------
// 64 tokens/block, 4 waves x 16 rows. x fp32 2-deep reg prefetch -> bf16 LDS;
// W gl_lds double-buffered. One barrier per K-step. Fully unrolled (static regs).
__global__ __launch_bounds__(256) void k_proj(
        const float* __restrict__ x,
        const short* __restrict__ WkT, const short* __restrict__ WvT,
        short* __restrict__ Kbuf, short* __restrict__ VT) {
    __shared__ short xl[2][64 * 64];    // 8KB each, swizzled, row=128B
    __shared__ short wl[2][128 * 64];   // 16KB each, swizzled, row=128B

    const int tid = threadIdx.x;
    const int lane = tid & 63;
    const int wv = tid >> 6;
    const int lr = lane & 15, g = lane >> 4;
    const int side = blockIdx.x;        // 0 = K, 1 = V
    const int r0 = blockIdx.y * 64;
    const short* WT = side ? WvT : WkT;

    f32x4 acc[8];
#pragma unroll
    for (int i = 0; i < 8; ++i) acc[i] = (f32x4){0.f, 0.f, 0.f, 0.f};

    // x staging geometry (per thread: 32B of the 64x64 bf16 tile image)
    int xo[2], xrow[2], xcolU[2];
#pragma unroll
    for (int j = 0; j < 2; ++j) {
        xo[j] = tid * 32 + j * 16;
        xrow[j] = xo[j] >> 7;
        xcolU[j] = (xo[j] & 127) ^ ((xrow[j] & 7) << 4);
    }
    f32x4 xr[2][2][2];  // [set][j][half] — all indices static after full unroll

#define XLOAD(s, set)                                                                \
    {                                                                                \
        _Pragma("unroll") for (int j = 0; j < 2; ++j) {                              \
            const float* sp = x + (size_t)(r0 + xrow[j]) * ED + (s) * 64 + (xcolU[j] >> 1); \
            xr[set][j][0] = *reinterpret_cast<const f32x4*>(sp);                     \
            xr[set][j][1] = *reinterpret_cast<const f32x4*>(sp + 4);                 \
        }                                                                            \
    }
#define XWRITE(set, buf)                                                             \
    {                                                                                \
        _Pragma("unroll") for (int j = 0; j < 2; ++j) {                              \
            bf16x8 pk;                                                               \
            _Pragma("unroll") for (int i = 0; i < 8; ++i)                            \
                pk[i] = bf16rne(xr[set][j][i >> 2][i & 3]);                          \
            *reinterpret_cast<bf16x8*>((char*)&xl[buf][0] + xo[j]) = pk;             \
        }                                                                            \
    }

    // prologue: x(0), x(1) in regs; W(0) staged; x(0) -> LDS
    XLOAD(0, 0);
    XLOAD(1, 1);
    stage_tile<4, 7>((const char*)WT, &wl[0][0], ED * 2, tid, wv);
    XWRITE(0, 0);
    __syncthreads();

#pragma unroll
    for (int s = 0; s < 16; ++s) {
        const int cur = s & 1;
        if (s + 1 < 16) {
            stage_tile<4, 7>((const char*)WT + (size_t)(s + 1) * 128, &wl[cur ^ 1][0],
                             ED * 2, tid, wv);
            XWRITE((s + 1) & 1, cur ^ 1);   // x(s+1) loaded a full step ago
        }
        if (s + 2 < 16) XLOAD(s + 2, cur);  // set that held x(s) is free
        // compute from xl[cur], wl[cur]
        bf16x8 af[2];
#pragma unroll
        for (int ks = 0; ks < 2; ++ks)
            af[ks] = lds_rd7(&xl[cur][0], wv * 16 + lr, ks * 32 + g * 8);
#pragma unroll
        for (int ks = 0; ks < 2; ++ks)
#pragma unroll
            for (int nf = 0; nf < 8; ++nf) {
                bf16x8 bfr = lds_rd7(&wl[cur][0], nf * 16 + lr, ks * 32 + g * 8);
                acc[nf] = __builtin_amdgcn_mfma_f32_16x16x32_bf16(af[ks], bfr, acc[nf], 0, 0, 0);
            }
        __syncthreads();
    }
#undef XLOAD
#undef XWRITE

    // epilogue: C col = n (lane&15 + 16nf), row = token (4g+r)
    const int mb = r0 + wv * 16 + 4 * g;
    if (side == 0) {
#pragma unroll
        for (int nf = 0; nf < 8; ++nf) {
            const int n = nf * 16 + lr;
#pragma unroll
            for (int r = 0; r < 4; ++r)
                Kbuf[(size_t)(mb + r) * HS + n] = bf16rne(acc[nf][r]);
        }
    } else {
        const int b = mb >> 11, tt = mb & (TT - 1);
#pragma unroll
        for (int nf = 0; nf < 8; ++nf) {
            const int n = nf * 16 + lr;
            bf16x4 o;
#pragma unroll
            for (int r = 0; r < 4; ++r) o[r] = bf16rne(acc[nf][r]);
            *reinterpret_cast<bf16x4*>(&VT[((size_t)b * HS + n) * TT + tt]) = o;
        }
    }
}

// ---------- flash attention partials (q = k per reference bug) ----------
// 640 flat work items (batch, 64-row q-tile, kv-chunk), 4 waves x 16 q-rows.
// K AND V double-buffered, staged right after the single per-tile barrier.
__global__ __launch_bounds__(256) void k_attn(
        const short* __restrict__ Kbuf, const short* __restrict__ VT,
        float* __restrict__ Opart, float* __restrict__ ml) {
    __shared__ short kl[2][64 * 128];   // 16KB each, swizzled, row=256B
    __shared__ short vl[2][128 * 64];   // 16KB each, swizzled, row=128B
    __shared__ short plds[4][16][72];   // per-wave P^T staging

    const int tid = threadIdx.x;
    const int lane = tid & 63;
    const int wv = tid >> 6;
    const int lr = lane & 15, g = lane >> 4;

    const int bid = blockIdx.x;
    const int b = bid & 7;
    const int w = bid >> 3;             // 0..79, heavy-ish first
    int c, qt;
    if (w < 32)      { c = 0; qt = 31 - w; }
    else if (w < 56) { c = 1; qt = 31 - (w - 32); }
    else if (w < 72) { c = 2; qt = 31 - (w - 56); }
    else             { c = 3; qt = 31 - (w - 72); }
    const int t_begin = c * TPC;
    const int t_end = min(t_begin + TPC, qt + 1);

    const short* Kb = Kbuf + (size_t)b * TT * HS;
    const short* Vb = VT + (size_t)b * HS * TT;
    const int q0 = qt * 64 + wv * 16;

    // Q fragments (B operand), contiguous 16B per lane
    bf16x8 qf[4];
#pragma unroll
    for (int ks = 0; ks < 4; ++ks)
        qf[ks] = *reinterpret_cast<const bf16x8*>(&Kb[(size_t)(q0 + lr) * HS + ks * 32 + g * 8]);

    // prologue: stage tile t_begin (K and V)
    stage_tile<4, 8>((const char*)(Kb + (size_t)t_begin * 64 * HS), &kl[0][0], HS * 2, tid, wv);
    stage_tile<4, 7>((const char*)(Vb + t_begin * 64), &vl[0][0], TT * 2, tid, wv);
    __syncthreads();

    float mrun = -1e30f, lrun = 0.f;
    f32x4 oacc[8];
#pragma unroll
    for (int i = 0; i < 8; ++i) oacc[i] = (f32x4){0.f, 0.f, 0.f, 0.f};

    const float c1 = 0.08838834764831845f * 1.4426950408889634f;  // 1/sqrt(128)*log2(e)
    const int qrow = q0 + lr;
    int cur = 0;

    for (int t = t_begin; t < t_end; ++t) {
        const int kv0 = t * 64;
        if (t + 1 < t_end) {  // prefetch next tile into the other buffers
            stage_tile<4, 8>((const char*)(Kb + (size_t)(kv0 + 64) * HS), &kl[cur ^ 1][0],
                             HS * 2, tid, wv);
            stage_tile<4, 7>((const char*)(Vb + kv0 + 64), &vl[cur ^ 1][0], TT * 2, tid, wv);
        }

        // S^T = K_tile . Q^T  -> C: col=q (lane&15), row=kv (4g+r+16mf)
        f32x4 s[4];
#pragma unroll
        for (int i = 0; i < 4; ++i) s[i] = (f32x4){0.f, 0.f, 0.f, 0.f};
        __builtin_amdgcn_s_setprio(1);
#pragma unroll
        for (int ks = 0; ks < 4; ++ks) {
            bf16x8 kf[4];
#pragma unroll
            for (int mf = 0; mf < 4; ++mf)
                kf[mf] = lds_rd8(&kl[cur][0], mf * 16 + lr, ks * 32 + g * 8);
#pragma unroll
            for (int mf = 0; mf < 4; ++mf)
                s[mf] = __builtin_amdgcn_mfma_f32_16x16x32_bf16(kf[mf], qf[ks], s[mf], 0, 0, 0);
        }
        __builtin_amdgcn_s_setprio(0);

        // scale + causal mask + online softmax (2 shuffles per reduce)
        float pv[4][4];
        float tmax = -1e30f;
#pragma unroll
        for (int mf = 0; mf < 4; ++mf)
#pragma unroll
            for (int r = 0; r < 4; ++r) {
                const int kv = kv0 + mf * 16 + 4 * g + r;
                float v = s[mf][r] * c1;
                v = (kv <= qrow) ? v : -1e30f;
                pv[mf][r] = v;
                tmax = fmaxf(tmax, v);
            }
        tmax = fmaxf(tmax, __shfl_xor(tmax, 16));
        tmax = fmaxf(tmax, __shfl_xor(tmax, 32));
        const float mnew = fmaxf(mrun, tmax);
        const float alpha = exp2f(mrun - mnew);
        mrun = mnew;
        float tsum = 0.f;
#pragma unroll
        for (int mf = 0; mf < 4; ++mf)
#pragma unroll
            for (int r = 0; r < 4; ++r) {
                const float p = exp2f(pv[mf][r] - mnew);
                pv[mf][r] = p;
                tsum += p;
            }
        tsum += __shfl_xor(tsum, 16);
        tsum += __shfl_xor(tsum, 32);
        lrun = lrun * alpha + tsum;
#pragma unroll
        for (int i = 0; i < 8; ++i) oacc[i] *= alpha;

        // P^T -> plds (wave-private, no barrier needed)
#pragma unroll
        for (int mf = 0; mf < 4; ++mf) {
            bf16x4 pk;
#pragma unroll
            for (int r = 0; r < 4; ++r) pk[r] = bf16rne(pv[mf][r]);
            *reinterpret_cast<bf16x4*>(&plds[wv][lr][mf * 16 + g * 4]) = pk;
        }
        // O^T += V^T_tile . P^T
        __builtin_amdgcn_s_setprio(1);
#pragma unroll
        for (int ks = 0; ks < 2; ++ks) {
            bf16x8 pf = *reinterpret_cast<const bf16x8*>(&plds[wv][lr][ks * 32 + g * 8]);
            bf16x8 vf[8];
#pragma unroll
            for (int mf = 0; mf < 8; ++mf)
                vf[mf] = lds_rd7(&vl[cur][0], mf * 16 + lr, ks * 32 + g * 8);
#pragma unroll
            for (int mf = 0; mf < 8; ++mf)
                oacc[mf] = __builtin_amdgcn_mfma_f32_16x16x32_bf16(vf[mf], pf, oacc[mf], 0, 0, 0);
        }
        __builtin_amdgcn_s_setprio(0);

        __syncthreads();  // everyone done reading cur; next-tile staging drained
        cur ^= 1;
    }

    // store unnormalized partial O^T + (m, l)
    const int row = b * TT + q0 + lr;
    const size_t pidx = (size_t)c * NROWS + row;
    float* op = Opart + pidx * HS;
#pragma unroll
    for (int mf = 0; mf < 8; ++mf)
        *reinterpret_cast<f32x4*>(&op[mf * 16 + g * 4]) = oacc[mf];
    if (lane < 16) {
        ml[pidx * 2] = mrun;
        ml[pidx * 2 + 1] = lrun;
    }
}

// ---------- merge split-KV partials (guard unwritten chunks) ----------
__global__ __launch_bounds__(256) void k_merge(const float* __restrict__ Opart,
                                               const float* __restrict__ ml,
                                               float* __restrict__ out) {
    const int idx = blockIdx.x * 256 + threadIdx.x;  // NROWS*32
    const int row = idx >> 5;
    const int h4 = (idx & 31) * 4;
    const int qt64 = (row & (TT - 1)) >> 6;
    const int nvalid = (qt64 >> 3) + 1;  // ceil((qt64+1)/8)
    float m[CHUNKS], l[CHUNKS];
    float M = -1e30f;
#pragma unroll
    for (int c = 0; c < CHUNKS; ++c) {
        const bool valid = c < nvalid;
        const size_t p = (size_t)c * NROWS + row;
        m[c] = valid ? ml[p * 2] : -1e30f;
        l[c] = valid ? ml[p * 2 + 1] : 0.f;
        M = fmaxf(M, m[c]);
    }
    float denom = 0.f;
    f32x4 o = (f32x4){0.f, 0.f, 0.f, 0.f};
#pragma unroll
    for (int c = 0; c < CHUNKS; ++c) {
        const bool valid = c < nvalid;
        const float wgt = valid ? exp2f(m[c] - M) : 0.f;
        denom += wgt * l[c];
        if (valid) {
            f32x4 p = *reinterpret_cast<const f32x4*>(
                &Opart[((size_t)c * NROWS + row) * HS + h4]);
            o += p * wgt;
        }
    }
    const float inv = 1.0f / denom;
    *reinterpret_cast<f32x4*>(&out[(size_t)row * HS + h4]) = o * inv;
}

extern "C" void kernel_launch(void* const* d_in, const int* in_sizes, int n_in,
                              void* d_out, int out_size, void* d_ws, size_t ws_size,
                              hipStream_t stream) {
    (void)in_sizes; (void)n_in; (void)out_size; (void)ws_size;
    const float* x  = (const float*)d_in[0];
    const float* Wk = (const float*)d_in[1];
    // d_in[2] = W_query: unused (faithful to the reference's q = key(x) bug)
    const float* Wv = (const float*)d_in[3];
    float* out = (float*)d_out;

    char* ws = (char*)d_ws;
    short* Kbuf = (short*)ws;                                    // 4 MiB bf16 [16384][128]
    short* VT   = (short*)(ws + (size_t)NROWS * HS * 2);         // 4 MiB bf16 [8][128][2048]
    short* WkT  = (short*)(ws + 2 * (size_t)NROWS * HS * 2);     // 256 KiB
    short* WvT  = WkT + (size_t)HS * ED;                         // 256 KiB
    float* Opart = (float*)(WvT + (size_t)HS * ED);              // 32 MiB
    float* mlb   = Opart + (size_t)CHUNKS * NROWS * HS;          // 512 KiB

    hipLaunchKernelGGL(k_wtrans, dim3(64, 2), dim3(256), 0, stream, Wk, Wv, WkT, WvT);
    hipLaunchKernelGGL(k_proj, dim3(2, NROWS / 64), dim3(256), 0, stream, x, WkT, WvT, Kbuf, VT);
    hipLaunchKernelGGL(k_attn, dim3(640), dim3(256), 0, stream, Kbuf, VT, Opart, mlb);
    hipLaunchKernelGGL(k_merge, dim3(NROWS * 32 / 256), dim3(256), 0, stream, Opart, mlb, out);
}

// Round 6
// 165.279 us; speedup vs baseline: 1.0001x; 1.0001x over previous
//
#include <hip/hip_runtime.h>
#include <hip/hip_bf16.h>

typedef __attribute__((ext_vector_type(8))) short bf16x8;
typedef __attribute__((ext_vector_type(4))) short bf16x4;
typedef __attribute__((ext_vector_type(4))) float f32x4;

#define HS 128
#define ED 1024
#define TT 2048
#define NBATCH 8
#define NROWS (NBATCH * TT)  // 16384
#define CHUNKS 4             // max kv chunks of 512
#define TPC 8                // 64-kv tiles per chunk

__device__ __forceinline__ short bf16rne(float f) {
    unsigned u = __builtin_bit_cast(unsigned, f);
    u = u + 0x7fffu + ((u >> 16) & 1u);
    return (short)(u >> 16);
}

// counted vmem wait — literal strings, "memory" clobber orders all LDS/global ops
template <int N>
__device__ __forceinline__ void vmwait() {
    if constexpr (N == 0)      asm volatile("s_waitcnt vmcnt(0)" ::: "memory");
    else if constexpr (N == 4) asm volatile("s_waitcnt vmcnt(4)" ::: "memory");
    else                       asm volatile("s_waitcnt vmcnt(8)" ::: "memory");
}
// raw barrier: does NOT drain vmcnt (unlike __syncthreads) — loads stay in flight.
// RACE DISCIPLINE: any gl_lds staging must be covered by a per-wave vmwait
// executed BEFORE a barrier; consumers read only AFTER that barrier.
__device__ __forceinline__ void lds_barrier() {
    asm volatile("s_waitcnt lgkmcnt(0)" ::: "memory");
    __builtin_amdgcn_s_barrier();
}

// async global->LDS, 16B per lane. LDS dest must be wave-uniform (HW adds lane*16).
__device__ __forceinline__ void gl_lds16(const void* g, void* l) {
    __builtin_amdgcn_global_load_lds(
        (const __attribute__((address_space(1))) unsigned int*)g,
        (__attribute__((address_space(3))) unsigned int*)l, 16, 0, 0);
}

// Stage NCALLS*4KB of a row-major global tile into XOR-swizzled LDS (NCALLS vmem/wave).
// LDS row = 1<<RBL2 bytes; swizzle: colU = colS ^ ((row&7)<<4) (involution).
// Linear LDS dest + inverse-swizzled global source (rule 21).
template <int NCALLS, int RBL2>
__device__ __forceinline__ void stage_tile(const char* gbase, void* lds,
                                           int gpitch, int tid, int wv) {
#pragma unroll
    for (int c = 0; c < NCALLS; ++c) {
        const int o = c * 4096 + tid * 16;
        const int row = o >> RBL2;
        const int colU = (o & ((1 << RBL2) - 1)) ^ ((row & 7) << 4);
        const char* g = gbase + (size_t)row * gpitch + colU;
        char* l = (char*)lds + c * 4096 + wv * 1024;  // wave-uniform
        gl_lds16(g, l);
    }
}

// swizzled ds_read of a bf16x8 fragment
__device__ __forceinline__ bf16x8 lds_rd7(const short* lds, int row, int colE) {
    const int o = (row << 7) + (((colE * 2) & 127) ^ ((row & 7) << 4));
    return *reinterpret_cast<const bf16x8*>((const char*)lds + o);
}
__device__ __forceinline__ bf16x8 lds_rd8(const short* lds, int row, int colE) {
    const int o = (row << 8) + (((colE * 2) & 255) ^ ((row & 7) << 4));
    return *reinterpret_cast<const bf16x8*>((const char*)lds + o);
}

// ---------- W transpose: [1024][128] f32 -> [128][1024] bf16 ----------
__global__ void k_wtrans(const float* __restrict__ Wk, const float* __restrict__ Wv,
                         short* __restrict__ WkT, short* __restrict__ WvT) {
    const float* W = blockIdx.y ? Wv : Wk;
    short* WT = blockIdx.y ? WvT : WkT;
    __shared__ float tile[16][128];
    const int k0 = blockIdx.x * 16;
    const int t = threadIdx.x;
#pragma unroll
    for (int i = 0; i < 8; ++i) {
        int idx = t + i * 256;
        tile[idx >> 7][idx & 127] = W[(size_t)(k0 + (idx >> 7)) * HS + (idx & 127)];
    }
    __syncthreads();
    const int n = t >> 1;
    const int h = (t & 1) * 8;
    bf16x8 o;
#pragma unroll
    for (int i = 0; i < 8; ++i) o[i] = bf16rne(tile[h + i][n]);
    *reinterpret_cast<bf16x8*>(&WT[(size_t)n * ED + k0 + h]) = o;
}

// ---------- projection: one side per block. grid (2 sides, 256 row-tiles) ----------
// 64 tokens/block, 4 waves x 16 rows. x: 2-deep register prefetch -> bf16 ds_write
// (double-buffered xl). W: depth-1 gl_lds (double-buffered wl). One barrier/step.
// vmwait<4> keeps only the freshest x-load group in flight (HBM latency hidden);
// every retired group is guaranteed cross-wave by the following barrier.
__global__ __launch_bounds__(256) void k_proj(
        const float* __restrict__ x,
        const short* __restrict__ WkT, const short* __restrict__ WvT,
        short* __restrict__ Kbuf, short* __restrict__ VT) {
    __shared__ short xl[2][64 * 64];    // 8KB each, swizzled, row=128B
    __shared__ short wl[2][128 * 64];   // 16KB each, swizzled, row=128B

    const int tid = threadIdx.x;
    const int lane = tid & 63;
    const int wv = tid >> 6;
    const int lr = lane & 15, g = lane >> 4;
    const int side = blockIdx.x;        // 0 = K, 1 = V
    const int r0 = blockIdx.y * 64;
    const short* WT = side ? WvT : WkT;

    f32x4 acc[8];
#pragma unroll
    for (int i = 0; i < 8; ++i) acc[i] = (f32x4){0.f, 0.f, 0.f, 0.f};

    // x staging geometry (per thread: 32B of the 64x64 bf16 tile image)
    int xo[2], xrow[2], xcolU[2];
#pragma unroll
    for (int j = 0; j < 2; ++j) {
        xo[j] = tid * 32 + j * 16;
        xrow[j] = xo[j] >> 7;
        xcolU[j] = (xo[j] & 127) ^ ((xrow[j] & 7) << 4);
    }
    f32x4 xr[2][2][2];  // [set][j][half] — static indices after full unroll

#define XLOAD(s, set)                                                                \
    {                                                                                \
        _Pragma("unroll") for (int j = 0; j < 2; ++j) {                              \
            const float* sp = x + (size_t)(r0 + xrow[j]) * ED + (s) * 64 + (xcolU[j] >> 1); \
            xr[set][j][0] = *reinterpret_cast<const f32x4*>(sp);                     \
            xr[set][j][1] = *reinterpret_cast<const f32x4*>(sp + 4);                 \
        }                                                                            \
    }
#define XWRITE(set, buf)                                                             \
    {                                                                                \
        _Pragma("unroll") for (int j = 0; j < 2; ++j) {                              \
            bf16x8 pk;                                                               \
            _Pragma("unroll") for (int i = 0; i < 8; ++i)                            \
                pk[i] = bf16rne(xr[set][j][i >> 2][i & 3]);                          \
            *reinterpret_cast<bf16x8*>((char*)&xl[buf][0] + xo[j]) = pk;             \
        }                                                                            \
    }

    // prologue: x(0),x(1) to regs; W(0) staged; drain; x(0)->LDS; fence.
    XLOAD(0, 0);
    XLOAD(1, 1);
    stage_tile<4, 7>((const char*)WT, &wl[0][0], ED * 2, tid, wv);
    vmwait<0>();        // x(0),x(1),W(0) all arrived (this wave)
    XWRITE(0, 0);
    lds_barrier();      // cross-wave: W(0) + xl[0] visible

#pragma unroll
    for (int s = 0; s < 16; ++s) {
        // issue: W(s+1) stage (depth-1, L2-hot), x(s+2) loads (depth-2, HBM)
        if (s + 1 < 16)
            stage_tile<4, 7>((const char*)WT + (size_t)(s + 1) * 128,
                             &wl[(s + 1) & 1][0], ED * 2, tid, wv);
        if (s + 2 < 16) XLOAD(s + 2, s & 1);  // set s&1 freed by XWRITE(s) last step
        // compute step s from xl[s&1], wl[s&1] (both fenced by previous barrier)
        bf16x8 af[2];
#pragma unroll
        for (int ks = 0; ks < 2; ++ks)
            af[ks] = lds_rd7(&xl[s & 1][0], wv * 16 + lr, ks * 32 + g * 8);
#pragma unroll
        for (int ks = 0; ks < 2; ++ks)
#pragma unroll
            for (int nf = 0; nf < 8; ++nf) {
                bf16x8 bfr = lds_rd7(&wl[s & 1][0], nf * 16 + lr, ks * 32 + g * 8);
                acc[nf] = __builtin_amdgcn_mfma_f32_16x16x32_bf16(af[ks], bfr, acc[nf], 0, 0, 0);
            }
        // retire x(s+1) and W(s+1); keep only x(s+2) (freshest, 4 ops) in flight
        if (s + 2 < 16) vmwait<4>();
        else            vmwait<0>();
        if (s + 1 < 16) XWRITE((s + 1) & 1, (s + 1) & 1);
        lds_barrier();  // transports this wave's vmwait guarantee to all waves
    }
#undef XLOAD
#undef XWRITE

    // epilogue: C col = n (lane&15 + 16nf), row = token (4g+r)
    const int mb = r0 + wv * 16 + 4 * g;
    if (side == 0) {
#pragma unroll
        for (int nf = 0; nf < 8; ++nf) {
            const int n = nf * 16 + lr;
#pragma unroll
            for (int r = 0; r < 4; ++r)
                Kbuf[(size_t)(mb + r) * HS + n] = bf16rne(acc[nf][r]);
        }
    } else {
        const int b = mb >> 11, tt = mb & (TT - 1);
#pragma unroll
        for (int nf = 0; nf < 8; ++nf) {
            const int n = nf * 16 + lr;
            bf16x4 o;
#pragma unroll
            for (int r = 0; r < 4; ++r) o[r] = bf16rne(acc[nf][r]);
            *reinterpret_cast<bf16x4*>(&VT[((size_t)b * HS + n) * TT + tt]) = o;
        }
    }
}

// ---------- flash attention partials (q = k per reference bug) ----------
// 640 flat work items (batch, 64-row q-tile, kv-chunk), 4 waves x 16 q-rows.
// 2-buf K/V, depth-1 counted pipeline, 2 barriers/tile:
//   stage(t+1); vmwait<8> (retire S(t), keep S(t+1) flying); barrier;  [arrival]
//   compute t; barrier.                                                [reads-done]
__global__ __launch_bounds__(256) void k_attn(
        const short* __restrict__ Kbuf, const short* __restrict__ VT,
        float* __restrict__ Opart, float* __restrict__ ml) {
    __shared__ short kl[2][64 * 128];   // 16KB each, swizzled, row=256B
    __shared__ short vl[2][128 * 64];   // 16KB each, swizzled, row=128B
    __shared__ short plds[4][16][72];   // per-wave P^T staging

    const int tid = threadIdx.x;
    const int lane = tid & 63;
    const int wv = tid >> 6;
    const int lr = lane & 15, g = lane >> 4;

    const int bid = blockIdx.x;
    const int b = bid & 7;
    const int w = bid >> 3;             // 0..79, heavy-ish first
    int c, qt;
    if (w < 32)      { c = 0; qt = 31 - w; }
    else if (w < 56) { c = 1; qt = 31 - (w - 32); }
    else if (w < 72) { c = 2; qt = 31 - (w - 56); }
    else             { c = 3; qt = 31 - (w - 72); }
    const int t_begin = c * TPC;
    const int t_end = min(t_begin + TPC, qt + 1);

    const short* Kb = Kbuf + (size_t)b * TT * HS;
    const short* Vb = VT + (size_t)b * HS * TT;
    const int q0 = qt * 64 + wv * 16;

    // Q fragments (B operand), contiguous 16B per lane — oldest vmem ops
    bf16x8 qf[4];
#pragma unroll
    for (int ks = 0; ks < 4; ++ks)
        qf[ks] = *reinterpret_cast<const bf16x8*>(&Kb[(size_t)(q0 + lr) * HS + ks * 32 + g * 8]);

    // prologue: stage tile t_begin into buf 0 (8 vmem/wave)
    stage_tile<4, 8>((const char*)(Kb + (size_t)t_begin * 64 * HS), &kl[0][0], HS * 2, tid, wv);
    stage_tile<4, 7>((const char*)(Vb + t_begin * 64), &vl[0][0], TT * 2, tid, wv);

    float mrun = -1e30f, lrun = 0.f;
    f32x4 oacc[8];
#pragma unroll
    for (int i = 0; i < 8; ++i) oacc[i] = (f32x4){0.f, 0.f, 0.f, 0.f};

    const float c1 = 0.08838834764831845f * 1.4426950408889634f;  // 1/sqrt(128)*log2(e)
    const int qrow = q0 + lr;

    for (int t = t_begin; t < t_end; ++t) {
        const int bi = (t - t_begin) & 1;
        // stage tile t+1 into the other buffer (read-done fenced by prev barrier)
        if (t + 1 < t_end) {
            stage_tile<4, 8>((const char*)(Kb + (size_t)(t + 1) * 64 * HS), &kl[bi ^ 1][0],
                             HS * 2, tid, wv);
            stage_tile<4, 7>((const char*)(Vb + (t + 1) * 64), &vl[bi ^ 1][0], TT * 2, tid, wv);
            vmwait<8>();   // retire S(t) (+qf); S(t+1)'s 8 stay in flight
        } else {
            vmwait<0>();   // last tile: retire S(t)
        }
        __builtin_amdgcn_s_barrier();  // arrival fence: all waves' S(t) landed

        const int kv0 = t * 64;
        // S^T = K_tile . Q^T  -> C: col=q (lane&15), row=kv (4g+r+16mf)
        f32x4 s[4];
#pragma unroll
        for (int i = 0; i < 4; ++i) s[i] = (f32x4){0.f, 0.f, 0.f, 0.f};
        __builtin_amdgcn_s_setprio(1);
#pragma unroll
        for (int ks = 0; ks < 4; ++ks) {
            bf16x8 kf[4];
#pragma unroll
            for (int mf = 0; mf < 4; ++mf)
                kf[mf] = lds_rd8(&kl[bi][0], mf * 16 + lr, ks * 32 + g * 8);
#pragma unroll
            for (int mf = 0; mf < 4; ++mf)
                s[mf] = __builtin_amdgcn_mfma_f32_16x16x32_bf16(kf[mf], qf[ks], s[mf], 0, 0, 0);
        }
        __builtin_amdgcn_s_setprio(0);

        // scale + causal mask + online softmax (2 shuffles per reduce)
        float pv[4][4];
        float tmax = -1e30f;
#pragma unroll
        for (int mf = 0; mf < 4; ++mf)
#pragma unroll
            for (int r = 0; r < 4; ++r) {
                const int kv = kv0 + mf * 16 + 4 * g + r;
                float v = s[mf][r] * c1;
                v = (kv <= qrow) ? v : -1e30f;
                pv[mf][r] = v;
                tmax = fmaxf(tmax, v);
            }
        tmax = fmaxf(tmax, __shfl_xor(tmax, 16));
        tmax = fmaxf(tmax, __shfl_xor(tmax, 32));
        const float mnew = fmaxf(mrun, tmax);
        const float alpha = exp2f(mrun - mnew);
        mrun = mnew;
        float tsum = 0.f;
#pragma unroll
        for (int mf = 0; mf < 4; ++mf)
#pragma unroll
            for (int r = 0; r < 4; ++r) {
                const float p = exp2f(pv[mf][r] - mnew);
                pv[mf][r] = p;
                tsum += p;
            }
        tsum += __shfl_xor(tsum, 16);
        tsum += __shfl_xor(tsum, 32);
        lrun = lrun * alpha + tsum;
#pragma unroll
        for (int i = 0; i < 8; ++i) oacc[i] *= alpha;

        // P^T -> plds (wave-private, no cross-wave hazard)
#pragma unroll
        for (int mf = 0; mf < 4; ++mf) {
            bf16x4 pk;
#pragma unroll
            for (int r = 0; r < 4; ++r) pk[r] = bf16rne(pv[mf][r]);
            *reinterpret_cast<bf16x4*>(&plds[wv][lr][mf * 16 + g * 4]) = pk;
        }
        // O^T += V^T_tile . P^T
        __builtin_amdgcn_s_setprio(1);
#pragma unroll
        for (int ks = 0; ks < 2; ++ks) {
            bf16x8 pf = *reinterpret_cast<const bf16x8*>(&plds[wv][lr][ks * 32 + g * 8]);
            bf16x8 vf[8];
#pragma unroll
            for (int mf = 0; mf < 8; ++mf)
                vf[mf] = lds_rd7(&vl[bi][0], mf * 16 + lr, ks * 32 + g * 8);
#pragma unroll
            for (int mf = 0; mf < 8; ++mf)
                oacc[mf] = __builtin_amdgcn_mfma_f32_16x16x32_bf16(vf[mf], pf, oacc[mf], 0, 0, 0);
        }
        __builtin_amdgcn_s_setprio(0);

        lds_barrier();  // reads-done fence: buf bi may be overwritten next iter
    }

    // store unnormalized partial O^T + (m, l)
    const int row = b * TT + q0 + lr;
    const size_t pidx = (size_t)c * NROWS + row;
    float* op = Opart + pidx * HS;
#pragma unroll
    for (int mf = 0; mf < 8; ++mf)
        *reinterpret_cast<f32x4*>(&op[mf * 16 + g * 4]) = oacc[mf];
    if (lane < 16) {
        ml[pidx * 2] = mrun;
        ml[pidx * 2 + 1] = lrun;
    }
}

// ---------- merge split-KV partials (guard unwritten chunks) ----------
__global__ __launch_bounds__(256) void k_merge(const float* __restrict__ Opart,
                                               const float* __restrict__ ml,
                                               float* __restrict__ out) {
    const int idx = blockIdx.x * 256 + threadIdx.x;  // NROWS*32
    const int row = idx >> 5;
    const int h4 = (idx & 31) * 4;
    const int qt64 = (row & (TT - 1)) >> 6;
    const int nvalid = (qt64 >> 3) + 1;  // ceil((qt64+1)/8)
    float m[CHUNKS], l[CHUNKS];
    float M = -1e30f;
#pragma unroll
    for (int c = 0; c < CHUNKS; ++c) {
        const bool valid = c < nvalid;
        const size_t p = (size_t)c * NROWS + row;
        m[c] = valid ? ml[p * 2] : -1e30f;
        l[c] = valid ? ml[p * 2 + 1] : 0.f;
        M = fmaxf(M, m[c]);
    }
    float denom = 0.f;
    f32x4 o = (f32x4){0.f, 0.f, 0.f, 0.f};
#pragma unroll
    for (int c = 0; c < CHUNKS; ++c) {
        const bool valid = c < nvalid;
        const float wgt = valid ? exp2f(m[c] - M) : 0.f;
        denom += wgt * l[c];
        if (valid) {
            f32x4 p = *reinterpret_cast<const f32x4*>(
                &Opart[((size_t)c * NROWS + row) * HS + h4]);
            o += p * wgt;
        }
    }
    const float inv = 1.0f / denom;
    *reinterpret_cast<f32x4*>(&out[(size_t)row * HS + h4]) = o * inv;
}

extern "C" void kernel_launch(void* const* d_in, const int* in_sizes, int n_in,
                              void* d_out, int out_size, void* d_ws, size_t ws_size,
                              hipStream_t stream) {
    (void)in_sizes; (void)n_in; (void)out_size; (void)ws_size;
    const float* x  = (const float*)d_in[0];
    const float* Wk = (const float*)d_in[1];
    // d_in[2] = W_query: unused (faithful to the reference's q = key(x) bug)
    const float* Wv = (const float*)d_in[3];
    float* out = (float*)d_out;

    char* ws = (char*)d_ws;
    short* Kbuf = (short*)ws;                                    // 4 MiB bf16 [16384][128]
    short* VT   = (short*)(ws + (size_t)NROWS * HS * 2);         // 4 MiB bf16 [8][128][2048]
    short* WkT  = (short*)(ws + 2 * (size_t)NROWS * HS * 2);     // 256 KiB
    short* WvT  = WkT + (size_t)HS * ED;                         // 256 KiB
    float* Opart = (float*)(WvT + (size_t)HS * ED);              // 32 MiB
    float* mlb   = Opart + (size_t)CHUNKS * NROWS * HS;          // 512 KiB

    hipLaunchKernelGGL(k_wtrans, dim3(64, 2), dim3(256), 0, stream, Wk, Wv, WkT, WvT);
    hipLaunchKernelGGL(k_proj, dim3(2, NROWS / 64), dim3(256), 0, stream, x, WkT, WvT, Kbuf, VT);
    hipLaunchKernelGGL(k_attn, dim3(640), dim3(256), 0, stream, Kbuf, VT, Opart, mlb);
    hipLaunchKernelGGL(k_merge, dim3(NROWS * 32 / 256), dim3(256), 0, stream, Opart, mlb, out);
}

// Round 7
// 162.651 us; speedup vs baseline: 1.0163x; 1.0162x over previous
//
#include <hip/hip_runtime.h>
#include <hip/hip_bf16.h>

typedef __attribute__((ext_vector_type(8))) short bf16x8;
typedef __attribute__((ext_vector_type(4))) short bf16x4;
typedef __attribute__((ext_vector_type(4))) float f32x4;

#define HS 128
#define ED 1024
#define TT 2048
#define NBATCH 8
#define NROWS (NBATCH * TT)  // 16384
#define CHUNKS 4             // max kv chunks of 512
#define TPC 8                // 64-kv tiles per chunk

__device__ __forceinline__ short bf16rne(float f) {
    unsigned u = __builtin_bit_cast(unsigned, f);
    u = u + 0x7fffu + ((u >> 16) & 1u);
    return (short)(u >> 16);
}
__device__ __forceinline__ float bf16tof(short s) {
    unsigned u = ((unsigned)(unsigned short)s) << 16;
    return __builtin_bit_cast(float, u);
}

// counted vmem wait — literal strings, "memory" clobber orders all LDS/global ops
template <int N>
__device__ __forceinline__ void vmwait() {
    if constexpr (N == 0)      asm volatile("s_waitcnt vmcnt(0)" ::: "memory");
    else if constexpr (N == 4) asm volatile("s_waitcnt vmcnt(4)" ::: "memory");
    else                       asm volatile("s_waitcnt vmcnt(8)" ::: "memory");
}
// raw barrier: does NOT drain vmcnt (unlike __syncthreads) — loads stay in flight.
// RACE DISCIPLINE: any gl_lds staging must be covered by a per-wave vmwait
// executed BEFORE a barrier; consumers read only AFTER that barrier.
__device__ __forceinline__ void lds_barrier() {
    asm volatile("s_waitcnt lgkmcnt(0)" ::: "memory");
    __builtin_amdgcn_s_barrier();
}

// async global->LDS, 16B per lane. LDS dest must be wave-uniform (HW adds lane*16).
__device__ __forceinline__ void gl_lds16(const void* g, void* l) {
    __builtin_amdgcn_global_load_lds(
        (const __attribute__((address_space(1))) unsigned int*)g,
        (__attribute__((address_space(3))) unsigned int*)l, 16, 0, 0);
}

// Stage NCALLS*4KB of a row-major global tile into XOR-swizzled LDS (NCALLS vmem/wave).
// LDS row = 1<<RBL2 bytes; swizzle: colU = colS ^ ((row&7)<<4) (involution).
// Linear LDS dest + inverse-swizzled global source (rule 21).
template <int NCALLS, int RBL2>
__device__ __forceinline__ void stage_tile(const char* gbase, void* lds,
                                           int gpitch, int tid, int wv) {
#pragma unroll
    for (int c = 0; c < NCALLS; ++c) {
        const int o = c * 4096 + tid * 16;
        const int row = o >> RBL2;
        const int colU = (o & ((1 << RBL2) - 1)) ^ ((row & 7) << 4);
        const char* g = gbase + (size_t)row * gpitch + colU;
        char* l = (char*)lds + c * 4096 + wv * 1024;  // wave-uniform
        gl_lds16(g, l);
    }
}

// swizzled ds_read of a bf16x8 fragment
__device__ __forceinline__ bf16x8 lds_rd7(const short* lds, int row, int colE) {
    const int o = (row << 7) + (((colE * 2) & 127) ^ ((row & 7) << 4));
    return *reinterpret_cast<const bf16x8*>((const char*)lds + o);
}
__device__ __forceinline__ bf16x8 lds_rd8(const short* lds, int row, int colE) {
    const int o = (row << 8) + (((colE * 2) & 255) ^ ((row & 7) << 4));
    return *reinterpret_cast<const bf16x8*>((const char*)lds + o);
}

// ---------- W transpose: [1024][128] f32 -> [128][1024] bf16 ----------
__global__ void k_wtrans(const float* __restrict__ Wk, const float* __restrict__ Wv,
                         short* __restrict__ WkT, short* __restrict__ WvT) {
    const float* W = blockIdx.y ? Wv : Wk;
    short* WT = blockIdx.y ? WvT : WkT;
    __shared__ float tile[16][128];
    const int k0 = blockIdx.x * 16;
    const int t = threadIdx.x;
#pragma unroll
    for (int i = 0; i < 8; ++i) {
        int idx = t + i * 256;
        tile[idx >> 7][idx & 127] = W[(size_t)(k0 + (idx >> 7)) * HS + (idx & 127)];
    }
    __syncthreads();
    const int n = t >> 1;
    const int h = (t & 1) * 8;
    bf16x8 o;
#pragma unroll
    for (int i = 0; i < 8; ++i) o[i] = bf16rne(tile[h + i][n]);
    *reinterpret_cast<bf16x8*>(&WT[(size_t)n * ED + k0 + h]) = o;
}

// ---------- projection: one side per block. grid (2 sides, 256 row-tiles) ----------
// 64 tokens/block, 4 waves x 16 rows. x loaded DIRECTLY into A-fragments from
// global (no LDS round-trip), depth-2 register prefetch. W: gl_lds triple-buffer,
// staged depth-2 (full-step slack). One barrier/step; steady-state vmcnt(8).
__global__ __launch_bounds__(256) void k_proj(
        const float* __restrict__ x,
        const short* __restrict__ WkT, const short* __restrict__ WvT,
        short* __restrict__ Kbuf, short* __restrict__ VT) {
    __shared__ short wl[3][128 * 64];   // 16KB each, swizzled, row=128B

    const int tid = threadIdx.x;
    const int lane = tid & 63;
    const int wv = tid >> 6;
    const int lr = lane & 15, g = lane >> 4;
    const int side = blockIdx.x;        // 0 = K, 1 = V
    const int r0 = blockIdx.y * 64;
    const short* WT = side ? WvT : WkT;
    const int m0 = r0 + wv * 16;        // this wave's 16 tokens

    f32x4 acc[8];
#pragma unroll
    for (int i = 0; i < 8; ++i) acc[i] = (f32x4){0.f, 0.f, 0.f, 0.f};

    // x A-fragment source: row m0+lr, cols s*64 + ks*32 + g*8 (8 consecutive fp32)
    const float* xbase = x + (size_t)(m0 + lr) * ED + g * 8;
    f32x4 xr[2][2][2];  // [set][ks][half] — static indices after full unroll

#define XLOAD(s, set)                                                          \
    {                                                                          \
        _Pragma("unroll") for (int ks = 0; ks < 2; ++ks) {                     \
            const float* sp = xbase + (s) * 64 + ks * 32;                      \
            xr[set][ks][0] = *reinterpret_cast<const f32x4*>(sp);              \
            xr[set][ks][1] = *reinterpret_cast<const f32x4*>(sp + 4);          \
        }                                                                      \
    }
#define XCVT(set, af)                                                          \
    {                                                                          \
        _Pragma("unroll") for (int ks = 0; ks < 2; ++ks)                       \
            _Pragma("unroll") for (int i = 0; i < 8; ++i)                      \
                af[ks][i] = bf16rne(xr[set][ks][i >> 2][i & 3]);               \
    }

    // prologue: x(0),x(1) -> regs; W(0),W(1) staged; retire W(0); fence.
    XLOAD(0, 0);
    XLOAD(1, 1);
    stage_tile<4, 7>((const char*)WT, &wl[0][0], ED * 2, tid, wv);
    stage_tile<4, 7>((const char*)WT + 128, &wl[1][0], ED * 2, tid, wv);
    vmwait<4>();        // retire x(0),x(1),W(0); W(1) stays in flight
    lds_barrier();      // cross-wave: wl[0] visible

#pragma unroll
    for (int s = 0; s < 16; ++s) {
        // consume x(s) from regs (compiler inserts the counted wait), free the set
        bf16x8 af[2];
        XCVT(s & 1, af);
        // issue depth-2 prefetches: x(s+2) into the freed set, W(s+2)
        if (s + 2 < 16) {
            XLOAD(s + 2, s & 1);
            stage_tile<4, 7>((const char*)WT + (size_t)(s + 2) * 128,
                             &wl[(s + 2) % 3][0], ED * 2, tid, wv);
        }
        // compute step s: B frags from wl[s%3] (fenced by previous barrier)
#pragma unroll
        for (int ks = 0; ks < 2; ++ks)
#pragma unroll
            for (int nf = 0; nf < 8; ++nf) {
                bf16x8 bfr = lds_rd7(&wl[s % 3][0], nf * 16 + lr, ks * 32 + g * 8);
                acc[nf] = __builtin_amdgcn_mfma_f32_16x16x32_bf16(af[ks], bfr, acc[nf], 0, 0, 0);
            }
        // retire W(s+1) (issued a full step ago); keep x(s+2)+W(s+2) in flight
        if (s + 2 < 16) vmwait<8>();
        else            vmwait<0>();
        lds_barrier();  // transports vmwait guarantee to all waves; reads-done fence
    }
#undef XLOAD
#undef XCVT

    // epilogue: C col = n (lane&15 + 16nf), row = token (4g+r)
    const int mb = m0 + 4 * g;
    if (side == 0) {
#pragma unroll
        for (int nf = 0; nf < 8; ++nf) {
            const int n = nf * 16 + lr;
#pragma unroll
            for (int r = 0; r < 4; ++r)
                Kbuf[(size_t)(mb + r) * HS + n] = bf16rne(acc[nf][r]);
        }
    } else {
        const int b = mb >> 11, tt = mb & (TT - 1);
#pragma unroll
        for (int nf = 0; nf < 8; ++nf) {
            const int n = nf * 16 + lr;
            bf16x4 o;
#pragma unroll
            for (int r = 0; r < 4; ++r) o[r] = bf16rne(acc[nf][r]);
            *reinterpret_cast<bf16x4*>(&VT[((size_t)b * HS + n) * TT + tt]) = o;
        }
    }
}

// ---------- flash attention partials (q = k per reference bug) ----------
// 640 flat work items (batch, 64-row q-tile, kv-chunk), 4 waves x 16 q-rows.
// 2-buf K/V, depth-1 counted pipeline, 2 barriers/tile:
//   stage(t+1); vmwait<8> (retire S(t), keep S(t+1) flying); barrier;  [arrival]
//   compute t; barrier.                                                [reads-done]
__global__ __launch_bounds__(256) void k_attn(
        const short* __restrict__ Kbuf, const short* __restrict__ VT,
        short* __restrict__ Opart, float* __restrict__ ml) {
    __shared__ short kl[2][64 * 128];   // 16KB each, swizzled, row=256B
    __shared__ short vl[2][128 * 64];   // 16KB each, swizzled, row=128B
    __shared__ short plds[4][16][72];   // per-wave P^T staging

    const int tid = threadIdx.x;
    const int lane = tid & 63;
    const int wv = tid >> 6;
    const int lr = lane & 15, g = lane >> 4;

    const int bid = blockIdx.x;
    const int b = bid & 7;
    const int w = bid >> 3;             // 0..79, heavy-ish first
    int c, qt;
    if (w < 32)      { c = 0; qt = 31 - w; }
    else if (w < 56) { c = 1; qt = 31 - (w - 32); }
    else if (w < 72) { c = 2; qt = 31 - (w - 56); }
    else             { c = 3; qt = 31 - (w - 72); }
    const int t_begin = c * TPC;
    const int t_end = min(t_begin + TPC, qt + 1);

    const short* Kb = Kbuf + (size_t)b * TT * HS;
    const short* Vb = VT + (size_t)b * HS * TT;
    const int q0 = qt * 64 + wv * 16;

    // Q fragments (B operand), contiguous 16B per lane — oldest vmem ops
    bf16x8 qf[4];
#pragma unroll
    for (int ks = 0; ks < 4; ++ks)
        qf[ks] = *reinterpret_cast<const bf16x8*>(&Kb[(size_t)(q0 + lr) * HS + ks * 32 + g * 8]);

    // prologue: stage tile t_begin into buf 0 (8 vmem/wave)
    stage_tile<4, 8>((const char*)(Kb + (size_t)t_begin * 64 * HS), &kl[0][0], HS * 2, tid, wv);
    stage_tile<4, 7>((const char*)(Vb + t_begin * 64), &vl[0][0], TT * 2, tid, wv);

    float mrun = -1e30f, lrun = 0.f;
    f32x4 oacc[8];
#pragma unroll
    for (int i = 0; i < 8; ++i) oacc[i] = (f32x4){0.f, 0.f, 0.f, 0.f};

    const float c1 = 0.08838834764831845f * 1.4426950408889634f;  // 1/sqrt(128)*log2(e)
    const int qrow = q0 + lr;

    for (int t = t_begin; t < t_end; ++t) {
        const int bi = (t - t_begin) & 1;
        // stage tile t+1 into the other buffer (read-done fenced by prev barrier)
        if (t + 1 < t_end) {
            stage_tile<4, 8>((const char*)(Kb + (size_t)(t + 1) * 64 * HS), &kl[bi ^ 1][0],
                             HS * 2, tid, wv);
            stage_tile<4, 7>((const char*)(Vb + (t + 1) * 64), &vl[bi ^ 1][0], TT * 2, tid, wv);
            vmwait<8>();   // retire S(t) (+qf); S(t+1)'s 8 stay in flight
        } else {
            vmwait<0>();   // last tile: retire S(t)
        }
        __builtin_amdgcn_s_barrier();  // arrival fence: all waves' S(t) landed

        const int kv0 = t * 64;
        // S^T = K_tile . Q^T  -> C: col=q (lane&15), row=kv (4g+r+16mf)
        f32x4 s[4];
#pragma unroll
        for (int i = 0; i < 4; ++i) s[i] = (f32x4){0.f, 0.f, 0.f, 0.f};
        __builtin_amdgcn_s_setprio(1);
#pragma unroll
        for (int ks = 0; ks < 4; ++ks) {
            bf16x8 kf[4];
#pragma unroll
            for (int mf = 0; mf < 4; ++mf)
                kf[mf] = lds_rd8(&kl[bi][0], mf * 16 + lr, ks * 32 + g * 8);
#pragma unroll
            for (int mf = 0; mf < 4; ++mf)
                s[mf] = __builtin_amdgcn_mfma_f32_16x16x32_bf16(kf[mf], qf[ks], s[mf], 0, 0, 0);
        }
        __builtin_amdgcn_s_setprio(0);

        // scale + causal mask + online softmax (2 shuffles per reduce)
        float pv[4][4];
        float tmax = -1e30f;
#pragma unroll
        for (int mf = 0; mf < 4; ++mf)
#pragma unroll
            for (int r = 0; r < 4; ++r) {
                const int kv = kv0 + mf * 16 + 4 * g + r;
                float v = s[mf][r] * c1;
                v = (kv <= qrow) ? v : -1e30f;
                pv[mf][r] = v;
                tmax = fmaxf(tmax, v);
            }
        tmax = fmaxf(tmax, __shfl_xor(tmax, 16));
        tmax = fmaxf(tmax, __shfl_xor(tmax, 32));
        const float mnew = fmaxf(mrun, tmax);
        const float alpha = exp2f(mrun - mnew);
        mrun = mnew;
        float tsum = 0.f;
#pragma unroll
        for (int mf = 0; mf < 4; ++mf)
#pragma unroll
            for (int r = 0; r < 4; ++r) {
                const float p = exp2f(pv[mf][r] - mnew);
                pv[mf][r] = p;
                tsum += p;
            }
        tsum += __shfl_xor(tsum, 16);
        tsum += __shfl_xor(tsum, 32);
        lrun = lrun * alpha + tsum;
#pragma unroll
        for (int i = 0; i < 8; ++i) oacc[i] *= alpha;

        // P^T -> plds (wave-private, no cross-wave hazard)
#pragma unroll
        for (int mf = 0; mf < 4; ++mf) {
            bf16x4 pk;
#pragma unroll
            for (int r = 0; r < 4; ++r) pk[r] = bf16rne(pv[mf][r]);
            *reinterpret_cast<bf16x4*>(&plds[wv][lr][mf * 16 + g * 4]) = pk;
        }
        // O^T += V^T_tile . P^T
        __builtin_amdgcn_s_setprio(1);
#pragma unroll
        for (int ks = 0; ks < 2; ++ks) {
            bf16x8 pf = *reinterpret_cast<const bf16x8*>(&plds[wv][lr][ks * 32 + g * 8]);
            bf16x8 vf[8];
#pragma unroll
            for (int mf = 0; mf < 8; ++mf)
                vf[mf] = lds_rd7(&vl[bi][0], mf * 16 + lr, ks * 32 + g * 8);
#pragma unroll
            for (int mf = 0; mf < 8; ++mf)
                oacc[mf] = __builtin_amdgcn_mfma_f32_16x16x32_bf16(vf[mf], pf, oacc[mf], 0, 0, 0);
        }
        __builtin_amdgcn_s_setprio(0);

        lds_barrier();  // reads-done fence: buf bi may be overwritten next iter
    }

    // store unnormalized partial O^T (bf16) + (m, l)
    const int row = b * TT + q0 + lr;
    const size_t pidx = (size_t)c * NROWS + row;
    short* op = Opart + pidx * HS;
#pragma unroll
    for (int mf = 0; mf < 8; ++mf) {
        bf16x4 ob;
#pragma unroll
        for (int r = 0; r < 4; ++r) ob[r] = bf16rne(oacc[mf][r]);
        *reinterpret_cast<bf16x4*>(&op[mf * 16 + g * 4]) = ob;
    }
    if (lane < 16) {
        ml[pidx * 2] = mrun;
        ml[pidx * 2 + 1] = lrun;
    }
}

// ---------- merge split-KV partials (guard unwritten chunks) ----------
__global__ __launch_bounds__(256) void k_merge(const short* __restrict__ Opart,
                                               const float* __restrict__ ml,
                                               float* __restrict__ out) {
    const int idx = blockIdx.x * 256 + threadIdx.x;  // NROWS*32
    const int row = idx >> 5;
    const int h4 = (idx & 31) * 4;
    const int qt64 = (row & (TT - 1)) >> 6;
    const int nvalid = (qt64 >> 3) + 1;  // ceil((qt64+1)/8)
    float m[CHUNKS], l[CHUNKS];
    float M = -1e30f;
#pragma unroll
    for (int c = 0; c < CHUNKS; ++c) {
        const bool valid = c < nvalid;
        const size_t p = (size_t)c * NROWS + row;
        m[c] = valid ? ml[p * 2] : -1e30f;
        l[c] = valid ? ml[p * 2 + 1] : 0.f;
        M = fmaxf(M, m[c]);
    }
    float denom = 0.f;
    f32x4 o = (f32x4){0.f, 0.f, 0.f, 0.f};
#pragma unroll
    for (int c = 0; c < CHUNKS; ++c) {
        const bool valid = c < nvalid;
        const float wgt = valid ? exp2f(m[c] - M) : 0.f;
        denom += wgt * l[c];
        if (valid) {
            bf16x4 pb = *reinterpret_cast<const bf16x4*>(
                &Opart[((size_t)c * NROWS + row) * HS + h4]);
#pragma unroll
            for (int j = 0; j < 4; ++j) o[j] += wgt * bf16tof(pb[j]);
        }
    }
    const float inv = 1.0f / denom;
    *reinterpret_cast<f32x4*>(&out[(size_t)row * HS + h4]) = o * inv;
}

extern "C" void kernel_launch(void* const* d_in, const int* in_sizes, int n_in,
                              void* d_out, int out_size, void* d_ws, size_t ws_size,
                              hipStream_t stream) {
    (void)in_sizes; (void)n_in; (void)out_size; (void)ws_size;
    const float* x  = (const float*)d_in[0];
    const float* Wk = (const float*)d_in[1];
    // d_in[2] = W_query: unused (faithful to the reference's q = key(x) bug)
    const float* Wv = (const float*)d_in[3];
    float* out = (float*)d_out;

    char* ws = (char*)d_ws;
    short* Kbuf = (short*)ws;                                    // 4 MiB bf16 [16384][128]
    short* VT   = (short*)(ws + (size_t)NROWS * HS * 2);         // 4 MiB bf16 [8][128][2048]
    short* WkT  = (short*)(ws + 2 * (size_t)NROWS * HS * 2);     // 256 KiB
    short* WvT  = WkT + (size_t)HS * ED;                         // 256 KiB
    short* Opart = WvT + (size_t)HS * ED;                        // 16 MiB bf16
    float* mlb   = (float*)(Opart + (size_t)CHUNKS * NROWS * HS);// 512 KiB

    hipLaunchKernelGGL(k_wtrans, dim3(64, 2), dim3(256), 0, stream, Wk, Wv, WkT, WvT);
    hipLaunchKernelGGL(k_proj, dim3(2, NROWS / 64), dim3(256), 0, stream, x, WkT, WvT, Kbuf, VT);
    hipLaunchKernelGGL(k_attn, dim3(640), dim3(256), 0, stream, Kbuf, VT, Opart, mlb);
    hipLaunchKernelGGL(k_merge, dim3(NROWS * 32 / 256), dim3(256), 0, stream, Opart, mlb, out);
}